// Round 1
// baseline (179.340 us; speedup 1.0000x reference)
//
#include <hip/hip_runtime.h>

static constexpr int NS    = 1024;   // N
static constexpr int KR    = 17;     // K
static constexpr int NROWS = NS * KR;

__device__ inline float wave_sum(float v) {
#pragma unroll
    for (int s = 32; s > 0; s >>= 1) v += __shfl_xor(v, s, 64);
    return v;
}
__device__ inline float wave_max(float v) {
#pragma unroll
    for (int s = 32; s > 0; s >>= 1) v = fmaxf(v, __shfl_xor(v, s, 64));
    return v;
}

// One 64-lane wave per row of length W. Computes:
//   flag = all(pred < 3)          (== max(pred) < 3)
//   loss = flag ? mean(bce) : mean(kld)
// kld folded:  sum_kld = T1/S - log(S) - T2/S + lse
//   with e_i = exp(10*gt_i - mg), S = sum e, T1 = sum e*(10*gt_i - mg),
//   T2 = sum e*pred_i, lse = logsumexp(pred)   (BETA = 1)
template <int W>
__global__ __launch_bounds__(256) void row_loss_kernel(
    const float* __restrict__ pred, const float* __restrict__ gt,
    float* __restrict__ loss, int* __restrict__ flag) {
    const int row  = (int)((blockIdx.x * (unsigned)blockDim.x + threadIdx.x) >> 6);
    const int lane = threadIdx.x & 63;
    if (row >= NROWS) return;

    const float2* p2 = (const float2*)(pred + (size_t)row * W);
    const float2* g2 = (const float2*)(gt   + (size_t)row * W);
    constexpr int EP = W / 128;  // float2 elements per lane (3 for 384, 4 for 512)

    float2 pv[EP], gv[EP];
#pragma unroll
    for (int j = 0; j < EP; ++j) {
        pv[j] = p2[lane + 64 * j];
        gv[j] = g2[lane + 64 * j];
    }

    // pass 1: maxes
    float mp = -1e30f, mg = -1e30f;
#pragma unroll
    for (int j = 0; j < EP; ++j) {
        mp = fmaxf(mp, fmaxf(pv[j].x, pv[j].y));
        mg = fmaxf(mg, fmaxf(gv[j].x, gv[j].y));
    }
    mp = wave_max(mp);
    mg = wave_max(mg) * 10.0f;  // max(10*g) = 10*max(g)

    // pass 2: sums
    float sp = 0.f, S = 0.f, T1 = 0.f, T2 = 0.f, bce = 0.f;
#pragma unroll
    for (int j = 0; j < EP; ++j) {
        float pe[2] = {pv[j].x, pv[j].y};
        float ge[2] = {gv[j].x, gv[j].y};
#pragma unroll
        for (int t = 0; t < 2; ++t) {
            float p   = pe[t];
            float g10 = 10.0f * ge[t];
            sp += __expf(p - mp);
            float d = g10 - mg;
            float e = __expf(d);
            S  += e;
            T1 += e * d;
            T2 += e * p;
            bce += fmaxf(p, 0.f) + log1pf(__expf(-fabsf(p))) - p * ge[t];
        }
    }
    sp = wave_sum(sp);
    S  = wave_sum(S);
    T1 = wave_sum(T1);
    T2 = wave_sum(T2);
    bce = wave_sum(bce);

    if (lane == 0) {
        const float inv = 1.0f / (float)W;
        float lse  = mp + __logf(sp);
        float kld  = (T1 / S - __logf(S) - T2 / S + lse) * inv;
        float bcem = bce * inv;
        bool lesser = (mp < 3.0f);
        loss[row] = lesser ? bcem : kld;
        flag[row] = lesser ? 1 : 0;
    }
}

// Per-sample: stable-argsort permutation (KLD rows first in original order,
// then BCE rows), dot with the sample's weight row, x + y.
__global__ __launch_bounds__(256) void combine_kernel(
    const float* __restrict__ lx, const int* __restrict__ fx,
    const float* __restrict__ ly, const int* __restrict__ fy,
    const float* __restrict__ w, float* __restrict__ sloss) {
    int n = blockIdx.x * blockDim.x + threadIdx.x;
    if (n >= NS) return;
    const float* wn = w + n * KR;
    float acc = 0.f;
    {
        const float* l = lx + n * KR;
        const int*   f = fx + n * KR;
        int pos = 0;
        for (int k = 0; k < KR; ++k) if (!f[k]) acc += l[k] * wn[pos++];
        for (int k = 0; k < KR; ++k) if (f[k])  acc += l[k] * wn[pos++];
    }
    {
        const float* l = ly + n * KR;
        const int*   f = fy + n * KR;
        int pos = 0;
        for (int k = 0; k < KR; ++k) if (!f[k]) acc += l[k] * wn[pos++];
        for (int k = 0; k < KR; ++k) if (f[k])  acc += l[k] * wn[pos++];
    }
    sloss[n] = acc;
}

// Deterministic final reduction: one block sums NS per-sample values, /K.
__global__ __launch_bounds__(256) void reduce_kernel(
    const float* __restrict__ sloss, float* __restrict__ out) {
    float v = 0.f;
    for (int i = threadIdx.x; i < NS; i += 256) v += sloss[i];
    v = wave_sum(v);
    __shared__ float wsm[4];
    if ((threadIdx.x & 63) == 0) wsm[threadIdx.x >> 6] = v;
    __syncthreads();
    if (threadIdx.x == 0) {
        out[0] = (wsm[0] + wsm[1] + wsm[2] + wsm[3]) * (1.0f / (float)KR);
    }
}

extern "C" void kernel_launch(void* const* d_in, const int* in_sizes, int n_in,
                              void* d_out, int out_size, void* d_ws, size_t ws_size,
                              hipStream_t stream) {
    const float* pred_x = (const float*)d_in[0];
    const float* pred_y = (const float*)d_in[1];
    const float* gt_x   = (const float*)d_in[2];
    const float* gt_y   = (const float*)d_in[3];
    const float* tw     = (const float*)d_in[4];

    // workspace layout (floats/ints, all 4 B): lx | ly | fx | fy | sloss
    float* lx    = (float*)d_ws;
    float* ly    = lx + NROWS;
    int*   fx    = (int*)(ly + NROWS);
    int*   fy    = fx + NROWS;
    float* sloss = (float*)(fy + NROWS);

    // 4 waves (rows) per 256-thread block
    const int row_blocks = (NROWS + 3) / 4;
    row_loss_kernel<384><<<row_blocks, 256, 0, stream>>>(pred_x, gt_x, lx, fx);
    row_loss_kernel<512><<<row_blocks, 256, 0, stream>>>(pred_y, gt_y, ly, fy);

    combine_kernel<<<(NS + 255) / 256, 256, 0, stream>>>(lx, fx, ly, fy, tw, sloss);
    reduce_kernel<<<1, 256, 0, stream>>>(sloss, (float*)d_out);
}